// Round 4
// baseline (157.719 us; speedup 1.0000x reference)
//
#include <hip/hip_runtime.h>
#include <math.h>

#define NATOMS 21
#define DESC 210
#define DPAD 224          // padded descriptor count
#define P4 112            // DPAD/2 — float4-packed descriptor pairs
#define NTRAIN 4096
#define NM 128

#define CC 0.0f
#define STDC 1.0f
// q = sqrt(5)/sig
#define QS 0.22360679774997896f
// 5/(3*sig^2)
#define KE 0.016666666666666666f

#define CHUNK1 16         // bjq rows per pass1 LDS chunk
#define NCH1 (P4 / CHUNK1)        // 7
#define TC2 128           // t per pass2 block
#define CH2 16            // t per pass2 LDS chunk
#define NCH2 (TC2 / CH2)          // 8

__device__ __forceinline__ void pair_ij(int p, int& i, int& j) {
    int ii = (int)((1.0f + sqrtf(1.0f + 8.0f * (float)p)) * 0.5f);
    while (ii * (ii - 1) / 2 > p) --ii;
    while ((ii + 1) * ii / 2 <= p) ++ii;
    i = ii;
    j = p - ii * (ii - 1) / 2;
}

// prep: blocks [0,448) transpose+pack xs/Jx into bjq and accumulate bsq/cj per t;
//       blocks [448,576) build per-molecule descriptors aT, asq.
__global__ __launch_bounds__(256, 2) void k_prep(const float* __restrict__ Rs,
                                                 const float* __restrict__ xs_train,
                                                 const float* __restrict__ Jx,
                                                 float4* __restrict__ bjq,
                                                 float* __restrict__ aT,
                                                 float* __restrict__ asq,
                                                 float* __restrict__ bsqA,
                                                 float* __restrict__ cjA) {
    __shared__ float smem[2 * 32 * 65 + 8];
    const int tid = threadIdx.x;
    const int bid = blockIdx.x;
    if (bid < 448) {
        float* ldsX = smem;
        float* ldsJ = smem + 32 * 65;
        const int bx = bid & 63;        // t tile
        const int by = bid >> 6;        // d tile (0..6)
        const int t0 = bx * 64;
        const int d0 = by * 32;
        #pragma unroll
        for (int k = 0; k < 8; ++k) {
            const int idx = tid + k * 256;        // 64t x 32d
            const int tt = idx >> 5;
            const int dd = idx & 31;
            const int d = d0 + dd;
            float xv = 0.0f, jv = 0.0f;
            if (d < DESC) {
                xv = QS * xs_train[(t0 + tt) * DESC + d];
                jv = Jx[(t0 + tt) * DESC + d];
            }
            ldsX[dd * 65 + tt] = xv;
            ldsJ[dd * 65 + tt] = jv;
        }
        __syncthreads();
        #pragma unroll
        for (int k = 0; k < 4; ++k) {
            const int idx = tid + k * 256;        // 16p x 64t
            const int pp = idx >> 6;
            const int tt = idx & 63;
            float4 v;
            v.x = ldsX[(2 * pp) * 65 + tt];
            v.y = ldsJ[(2 * pp) * 65 + tt];
            v.z = ldsX[(2 * pp + 1) * 65 + tt];
            v.w = ldsJ[(2 * pp + 1) * 65 + tt];
            bjq[(by * 16 + pp) * NTRAIN + t0 + tt] = v;
        }
        // per-t partials of sum_d b^2 and sum_d b*j over this 32-d tile
        if (tid < 64) {
            float sb = 0.0f, sc = 0.0f;
            #pragma unroll
            for (int dd = 0; dd < 32; ++dd) {
                const float b = ldsX[dd * 65 + tid];
                const float jj = ldsJ[dd * 65 + tid];
                sb = fmaf(b, b, sb);
                sc = fmaf(b, jj, sc);
            }
            atomicAdd(&bsqA[t0 + tid], sb);
            atomicAdd(&cjA[t0 + tid], sc);
        }
    } else {
        const int m = bid - 448;
        float* R = smem;
        float* red = smem + 64;
        if (tid < NATOMS * 3) R[tid] = Rs[m * NATOMS * 3 + tid];
        __syncthreads();
        float a2 = 0.0f;
        if (tid < DPAD) {
            float a = 0.0f;
            if (tid < DESC) {
                int i, j;
                pair_ij(tid, i, j);
                const float dx = R[i * 3 + 0] - R[j * 3 + 0];
                const float dy = R[i * 3 + 1] - R[j * 3 + 1];
                const float dz = R[i * 3 + 2] - R[j * 3 + 2];
                a = QS / sqrtf(dx * dx + dy * dy + dz * dz);
            }
            aT[tid * NM + m] = a;
            a2 = a * a;
        }
        #pragma unroll
        for (int off = 32; off > 0; off >>= 1) a2 += __shfl_down(a2, off, 64);
        if ((tid & 63) == 0) red[tid >> 6] = a2;
        __syncthreads();
        if (tid == 0) asq[m] = red[0] + red[1] + red[2] + red[3];
    }
}

// pass 1: P/Q inner products via LDS-double-buffered K loop.
// Block: 128 t-cols x 8 m (thread owns 4 m; half = tid>>7). Grid 32 x 16 = 512.
__global__ __launch_bounds__(256, 2) void k_pass1(const float4* __restrict__ bjq,
                                                  const float* __restrict__ aT,
                                                  const float* __restrict__ asq,
                                                  const float* __restrict__ bsqA,
                                                  const float* __restrict__ cjA,
                                                  float* __restrict__ w1Tm,
                                                  float* __restrict__ w2Tm,
                                                  float* __restrict__ EsAcc,
                                                  float* __restrict__ S1) {
    const int tid = threadIdx.x;
    const int tt = tid & 127;
    const int half = tid >> 7;          // wave-uniform
    const int t0 = blockIdx.x * 128;
    const int m0 = blockIdx.y * 8;
    const int t = t0 + tt;

    __shared__ __align__(16) float aS[DPAD * 8];            // 7 KB, [d][mi]
    __shared__ __align__(16) float4 bjS[2][CHUNK1 * 128];   // 64 KB

    #pragma unroll
    for (int k = 0; k < 7; ++k) {
        const int idx = tid + k * 256;
        aS[idx] = aT[(idx >> 3) * NM + m0 + (idx & 7)];
    }

    float4 rg[8];
    // stage chunk 0
    #pragma unroll
    for (int k = 0; k < 8; ++k) {
        const int idx = tid + k * 256;                      // 16 rows x 128 t
        rg[k] = bjq[(idx >> 7) * NTRAIN + t0 + (idx & 127)];
    }
    #pragma unroll
    for (int k = 0; k < 8; ++k) {
        const int idx = tid + k * 256;
        bjS[0][idx] = rg[k];
    }
    // issue chunk 1 loads (in flight across the barrier)
    #pragma unroll
    for (int k = 0; k < 8; ++k) {
        const int idx = tid + k * 256;
        rg[k] = bjq[(CHUNK1 + (idx >> 7)) * NTRAIN + t0 + (idx & 127)];
    }
    __syncthreads();

    float P[4] = {0.f, 0.f, 0.f, 0.f};
    float Q[4] = {0.f, 0.f, 0.f, 0.f};

    for (int c = 0; c < NCH1; ++c) {
        const int buf = c & 1;
        const int p0 = c * CHUNK1;
        #pragma unroll
        for (int u = 0; u < CHUNK1; ++u) {
            const float4 bj = bjS[buf][u * 128 + tt];
            const float4 aA = *reinterpret_cast<const float4*>(&aS[(p0 + u) * 16 + half * 4]);
            const float4 aB = *reinterpret_cast<const float4*>(&aS[(p0 + u) * 16 + 8 + half * 4]);
            P[0] = fmaf(aA.x, bj.x, P[0]); P[1] = fmaf(aA.y, bj.x, P[1]);
            P[2] = fmaf(aA.z, bj.x, P[2]); P[3] = fmaf(aA.w, bj.x, P[3]);
            Q[0] = fmaf(aA.x, bj.y, Q[0]); Q[1] = fmaf(aA.y, bj.y, Q[1]);
            Q[2] = fmaf(aA.z, bj.y, Q[2]); Q[3] = fmaf(aA.w, bj.y, Q[3]);
            P[0] = fmaf(aB.x, bj.z, P[0]); P[1] = fmaf(aB.y, bj.z, P[1]);
            P[2] = fmaf(aB.z, bj.z, P[2]); P[3] = fmaf(aB.w, bj.z, P[3]);
            Q[0] = fmaf(aB.x, bj.w, Q[0]); Q[1] = fmaf(aB.y, bj.w, Q[1]);
            Q[2] = fmaf(aB.z, bj.w, Q[2]); Q[3] = fmaf(aB.w, bj.w, Q[3]);
        }
        __syncthreads();
        if (c + 1 < NCH1) {
            #pragma unroll
            for (int k = 0; k < 8; ++k) {
                const int idx = tid + k * 256;
                bjS[1 - buf][idx] = rg[k];
            }
            if (c + 2 < NCH1) {
                #pragma unroll
                for (int k = 0; k < 8; ++k) {
                    const int idx = tid + k * 256;
                    rg[k] = bjq[((c + 2) * CHUNK1 + (idx >> 7)) * NTRAIN + t0 + (idx & 127)];
                }
            }
            __syncthreads();
        }
    }

    const float bsqv = bsqA[t];
    const float cjv = cjA[t];
    float esv[4], s1v[4];
    #pragma unroll
    for (int mi = 0; mi < 4; ++mi) {
        const int m = m0 + half * 4 + mi;
        float dist2 = asq[m] + bsqv - 2.0f * P[mi];
        dist2 = fmaxf(dist2, 0.0f);
        const float x = sqrtf(dist2);
        const float e = KE * expf(-x);
        const float dotv = Q[mi] - cjv;
        const float w1v = e * dotv;
        const float w2v = e * (1.0f + x);
        w1Tm[m * NTRAIN + t] = w1v;
        w2Tm[m * NTRAIN + t] = w2v;
        esv[mi] = w2v * dotv;
        s1v[mi] = w1v;
    }
    #pragma unroll
    for (int off = 32; off > 0; off >>= 1) {
        #pragma unroll
        for (int mi = 0; mi < 4; ++mi) {
            esv[mi] += __shfl_down(esv[mi], off, 64);
            s1v[mi] += __shfl_down(s1v[mi], off, 64);
        }
    }
    if ((tid & 63) == 0) {
        #pragma unroll
        for (int mi = 0; mi < 4; ++mi) {
            atomicAdd(&EsAcc[m0 + half * 4 + mi], esv[mi]);
            atomicAdd(&S1[m0 + half * 4 + mi], s1v[mi]);
        }
    }
}

// pass 2: G1[m][d] += sum_t w1[m][t]*b[t][d]; G2[m][d] += sum_t w2[m][t]*j[t][d].
// Thread per d; t-chunks of 16 staged from bjq into LDS; w via wave-uniform loads.
__global__ __launch_bounds__(256, 2) void k_pass2(const float4* __restrict__ bjq,
                                                  const float* __restrict__ w1Tm,
                                                  const float* __restrict__ w2Tm,
                                                  float* __restrict__ F1acc,
                                                  float* __restrict__ F2acc) {
    const int tid = threadIdx.x;
    const int t0 = blockIdx.x * TC2;
    const int m0 = blockIdx.y * 8;
    const int d = (tid < DESC) ? tid : (DESC - 1);    // clamp; stores guarded below

    __shared__ __align__(16) float2 xjS[2][CH2 * 226];  // ~57.8 KB, row stride 226 (pad)

    float4 rg[7];
    // stage chunk 0 (112 p-rows x 16 t = 1792 float4; 7/thread)
    #pragma unroll
    for (int k = 0; k < 7; ++k) {
        const int idx = tid + k * 256;
        rg[k] = bjq[(idx >> 4) * NTRAIN + t0 + (idx & 15)];
    }
    #pragma unroll
    for (int k = 0; k < 7; ++k) {
        const int idx = tid + k * 256;
        *reinterpret_cast<float4*>(&xjS[0][(idx & 15) * 226 + 2 * (idx >> 4)]) = rg[k];
    }
    #pragma unroll
    for (int k = 0; k < 7; ++k) {
        const int idx = tid + k * 256;
        rg[k] = bjq[(idx >> 4) * NTRAIN + t0 + CH2 + (idx & 15)];
    }
    __syncthreads();

    float G1[8] = {0.f, 0.f, 0.f, 0.f, 0.f, 0.f, 0.f, 0.f};
    float G2[8] = {0.f, 0.f, 0.f, 0.f, 0.f, 0.f, 0.f, 0.f};

    for (int c = 0; c < NCH2; ++c) {
        const int buf = c & 1;
        const int tg = t0 + c * CH2;
        #pragma unroll
        for (int rq = 0; rq < 4; ++rq) {
            // wave-uniform w loads (16B aligned, 4 t each)
            float4 w1v[8], w2v[8];
            #pragma unroll
            for (int mi = 0; mi < 8; ++mi) {
                w1v[mi] = *reinterpret_cast<const float4*>(&w1Tm[(m0 + mi) * NTRAIN + tg + rq * 4]);
                w2v[mi] = *reinterpret_cast<const float4*>(&w2Tm[(m0 + mi) * NTRAIN + tg + rq * 4]);
            }
            #pragma unroll
            for (int rr = 0; rr < 4; ++rr) {
                const float2 xj = xjS[buf][(rq * 4 + rr) * 226 + d];
                #pragma unroll
                for (int mi = 0; mi < 8; ++mi) {
                    const float* w1f = reinterpret_cast<const float*>(&w1v[mi]);
                    const float* w2f = reinterpret_cast<const float*>(&w2v[mi]);
                    G1[mi] = fmaf(w1f[rr], xj.x, G1[mi]);
                    G2[mi] = fmaf(w2f[rr], xj.y, G2[mi]);
                }
            }
        }
        __syncthreads();
        if (c + 1 < NCH2) {
            #pragma unroll
            for (int k = 0; k < 7; ++k) {
                const int idx = tid + k * 256;
                *reinterpret_cast<float4*>(&xjS[1 - buf][(idx & 15) * 226 + 2 * (idx >> 4)]) = rg[k];
            }
            if (c + 2 < NCH2) {
                #pragma unroll
                for (int k = 0; k < 7; ++k) {
                    const int idx = tid + k * 256;
                    rg[k] = bjq[(idx >> 4) * NTRAIN + t0 + (c + 2) * CH2 + (idx & 15)];
                }
            }
            __syncthreads();
        }
    }

    if (tid < DESC) {
        #pragma unroll
        for (int mi = 0; mi < 8; ++mi) {
            atomicAdd(&F1acc[(m0 + mi) * DESC + tid], G1[mi]);
            atomicAdd(&F2acc[(m0 + mi) * DESC + tid], G2[mi]);
        }
    }
}

// final assembly — coef, force scatter, Es
__global__ __launch_bounds__(256) void k_final(const float* __restrict__ Rs,
                                               const float* __restrict__ aT,
                                               const float* __restrict__ S1,
                                               const float* __restrict__ EsAcc,
                                               const float* __restrict__ F1acc,
                                               const float* __restrict__ F2acc,
                                               float* __restrict__ out) {
    const int m = blockIdx.x;
    __shared__ float R[NATOMS * 3];
    __shared__ float FsL[NATOMS * 3];
    const int tid = threadIdx.x;
    if (tid < NATOMS * 3) {
        R[tid] = Rs[m * NATOMS * 3 + tid];
        FsL[tid] = 0.0f;
    }
    __syncthreads();
    if (tid < DESC) {
        int i, j;
        pair_ij(tid, i, j);
        const float dx = R[i * 3 + 0] - R[j * 3 + 0];
        const float dy = R[i * 3 + 1] - R[j * 3 + 1];
        const float dz = R[i * 3 + 2] - R[j * 3 + 2];
        const float r2 = dx * dx + dy * dy + dz * dz;
        const float rinv = 1.0f / sqrtf(r2);
        const float a = aT[tid * NM + m];  // q/r
        const float F1 = a * S1[m] - F1acc[m * DESC + tid];
        const float Fx = (F1 - F2acc[m * DESC + tid]) * STDC;
        const float coef = Fx * (rinv * rinv * rinv);
        atomicAdd(&FsL[j * 3 + 0], coef * dx);
        atomicAdd(&FsL[j * 3 + 1], coef * dy);
        atomicAdd(&FsL[j * 3 + 2], coef * dz);
        atomicAdd(&FsL[i * 3 + 0], -coef * dx);
        atomicAdd(&FsL[i * 3 + 1], -coef * dy);
        atomicAdd(&FsL[i * 3 + 2], -coef * dz);
    }
    __syncthreads();
    if (tid < NATOMS * 3) out[NM + m * NATOMS * 3 + tid] = FsL[tid];
    if (tid == 0) out[m] = CC + (EsAcc[m] / QS) * STDC;
}

extern "C" void kernel_launch(void* const* d_in, const int* in_sizes, int n_in,
                              void* d_out, int out_size, void* d_ws, size_t ws_size,
                              hipStream_t stream) {
    const float* Rs = (const float*)d_in[0];
    const float* xs_train = (const float*)d_in[1];
    const float* Jx = (const float*)d_in[2];
    float* out = (float*)d_out;
    float* ws = (float*)d_ws;

    // zeroed prefix
    float* F1acc = ws;                         // 26880
    float* F2acc = ws + 26880;                 // 26880
    float* EsAcc = ws + 53760;                 // 128
    float* S1 = ws + 53888;                    // 128
    float* bsqA = ws + 54016;                  // 4096
    float* cjA = ws + 58112;                   // 4096  -> zero block ends at 62208
    // non-zeroed
    float* aT = ws + 62208;                    // 224*128 = 28672
    float* asq = ws + 90880;                   // 128
    float4* bjq = (float4*)(ws + 91008);       // 112*4096 float4 = 1835008 floats
    float* w1Tm = ws + 1926016;                // 524288
    float* w2Tm = ws + 2450304;                // 524288 -> end 2974592 floats (~11.9 MB)

    hipMemsetAsync(ws, 0, (size_t)62208 * sizeof(float), stream);

    k_prep<<<576, 256, 0, stream>>>(Rs, xs_train, Jx, bjq, aT, asq, bsqA, cjA);
    k_pass1<<<dim3(NTRAIN / 128, NM / 8), 256, 0, stream>>>(bjq, aT, asq, bsqA, cjA,
                                                            w1Tm, w2Tm, EsAcc, S1);
    k_pass2<<<dim3(NTRAIN / TC2, NM / 8), 256, 0, stream>>>(bjq, w1Tm, w2Tm,
                                                            F1acc, F2acc);
    k_final<<<NM, 256, 0, stream>>>(Rs, aT, S1, EsAcc, F1acc, F2acc, out);
}

// Round 5
// 103.217 us; speedup vs baseline: 1.5280x; 1.5280x over previous
//
#include <hip/hip_runtime.h>
#include <math.h>

#define NATOMS 21
#define DESC 210
#define DPAD 224          // padded descriptor count
#define P4 112            // DPAD/2 — float4-packed descriptor pairs
#define NTRAIN 4096
#define NM 128

#define CC 0.0f
#define STDC 1.0f
// q = sqrt(5)/sig
#define QS 0.22360679774997896f
// 5/(3*sig^2)
#define KE 0.016666666666666666f

__device__ __forceinline__ void pair_ij(int p, int& i, int& j) {
    int ii = (int)((1.0f + sqrtf(1.0f + 8.0f * (float)p)) * 0.5f);
    while (ii * (ii - 1) / 2 > p) --ii;
    while ((ii + 1) * ii / 2 <= p) ++ii;
    i = ii;
    j = p - ii * (ii - 1) / 2;
}

// prep: blocks [0,448) transpose+pack xs/Jx into bjq and accumulate bsq/cj per t;
//       blocks [448,576) build per-molecule descriptors aT, asq.
__global__ __launch_bounds__(256, 2) void k_prep(const float* __restrict__ Rs,
                                                 const float* __restrict__ xs_train,
                                                 const float* __restrict__ Jx,
                                                 float4* __restrict__ bjq,
                                                 float* __restrict__ aT,
                                                 float* __restrict__ asq,
                                                 float* __restrict__ bsqA,
                                                 float* __restrict__ cjA) {
    __shared__ float smem[2 * 32 * 65 + 8];
    const int tid = threadIdx.x;
    const int bid = blockIdx.x;
    if (bid < 448) {
        float* ldsX = smem;
        float* ldsJ = smem + 32 * 65;
        const int bx = bid & 63;        // t tile
        const int by = bid >> 6;        // d tile (0..6)
        const int t0 = bx * 64;
        const int d0 = by * 32;
        #pragma unroll
        for (int k = 0; k < 8; ++k) {
            const int idx = tid + k * 256;        // 64t x 32d
            const int tt = idx >> 5;
            const int dd = idx & 31;
            const int d = d0 + dd;
            float xv = 0.0f, jv = 0.0f;
            if (d < DESC) {
                xv = QS * xs_train[(t0 + tt) * DESC + d];
                jv = Jx[(t0 + tt) * DESC + d];
            }
            ldsX[dd * 65 + tt] = xv;
            ldsJ[dd * 65 + tt] = jv;
        }
        __syncthreads();
        #pragma unroll
        for (int k = 0; k < 4; ++k) {
            const int idx = tid + k * 256;        // 16p x 64t
            const int pp = idx >> 6;
            const int tt = idx & 63;
            float4 v;
            v.x = ldsX[(2 * pp) * 65 + tt];
            v.y = ldsJ[(2 * pp) * 65 + tt];
            v.z = ldsX[(2 * pp + 1) * 65 + tt];
            v.w = ldsJ[(2 * pp + 1) * 65 + tt];
            bjq[(by * 16 + pp) * NTRAIN + t0 + tt] = v;
        }
        // per-t partials of sum_d b^2 and sum_d b*j over this 32-d tile
        if (tid < 64) {
            float sb = 0.0f, sc = 0.0f;
            #pragma unroll
            for (int dd = 0; dd < 32; ++dd) {
                const float b = ldsX[dd * 65 + tid];
                const float jj = ldsJ[dd * 65 + tid];
                sb = fmaf(b, b, sb);
                sc = fmaf(b, jj, sc);
            }
            atomicAdd(&bsqA[t0 + tid], sb);
            atomicAdd(&cjA[t0 + tid], sc);
        }
    } else {
        const int m = bid - 448;
        float* R = smem;
        float* red = smem + 64;
        if (tid < NATOMS * 3) R[tid] = Rs[m * NATOMS * 3 + tid];
        __syncthreads();
        float a2 = 0.0f;
        if (tid < DPAD) {
            float a = 0.0f;
            if (tid < DESC) {
                int i, j;
                pair_ij(tid, i, j);
                const float dx = R[i * 3 + 0] - R[j * 3 + 0];
                const float dy = R[i * 3 + 1] - R[j * 3 + 1];
                const float dz = R[i * 3 + 2] - R[j * 3 + 2];
                a = QS / sqrtf(dx * dx + dy * dy + dz * dz);
            }
            aT[tid * NM + m] = a;
            a2 = a * a;
        }
        #pragma unroll
        for (int off = 32; off > 0; off >>= 1) a2 += __shfl_down(a2, off, 64);
        if ((tid & 63) == 0) red[tid >> 6] = a2;
        __syncthreads();
        if (tid == 0) asq[m] = red[0] + red[1] + red[2] + red[3];
    }
}

// pass 1: P[m] = sum_d a[m,d]*b[t,d], Q[m] = sum_d a[m,d]*j[t,d] for 8 m per block.
// Simple single-BB loop, #pragma unroll 8 so the scheduler clusters 8 independent
// global float4 loads. a-slice in LDS, read as wave-uniform b128 broadcasts.
__global__ __launch_bounds__(256) void k_pass1(const float4* __restrict__ bjq,
                                               const float* __restrict__ aT,
                                               const float* __restrict__ asq,
                                               const float* __restrict__ bsqA,
                                               const float* __restrict__ cjA,
                                               float* __restrict__ w1Tm,
                                               float* __restrict__ w2Tm,
                                               float* __restrict__ EsAcc,
                                               float* __restrict__ S1) {
    const int tid = threadIdx.x;
    const int t = blockIdx.x * 256 + tid;
    const int m0 = blockIdx.y * 8;
    __shared__ __align__(16) float aS[P4][16];  // [p][ {d=2p: m0..m7}, {d=2p+1: m0..m7} ]
    #pragma unroll
    for (int k = 0; k < 7; ++k) {
        const int idx = tid + k * 256;          // 112*16 = 1792
        const int p = idx >> 4;
        const int c = idx & 15;
        const int d = 2 * p + (c >> 3);
        aS[p][c] = aT[d * NM + m0 + (c & 7)];
    }
    __syncthreads();

    float P[8] = {0.f, 0.f, 0.f, 0.f, 0.f, 0.f, 0.f, 0.f};
    float Q[8] = {0.f, 0.f, 0.f, 0.f, 0.f, 0.f, 0.f, 0.f};

    #pragma unroll 8
    for (int p = 0; p < P4; ++p) {
        const float4 bj = bjq[p * NTRAIN + t];
        const float4 aA = *reinterpret_cast<const float4*>(&aS[p][0]);
        const float4 aB = *reinterpret_cast<const float4*>(&aS[p][4]);
        const float4 aC = *reinterpret_cast<const float4*>(&aS[p][8]);
        const float4 aD = *reinterpret_cast<const float4*>(&aS[p][12]);
        P[0] = fmaf(aA.x, bj.x, P[0]); P[1] = fmaf(aA.y, bj.x, P[1]);
        P[2] = fmaf(aA.z, bj.x, P[2]); P[3] = fmaf(aA.w, bj.x, P[3]);
        P[4] = fmaf(aB.x, bj.x, P[4]); P[5] = fmaf(aB.y, bj.x, P[5]);
        P[6] = fmaf(aB.z, bj.x, P[6]); P[7] = fmaf(aB.w, bj.x, P[7]);
        Q[0] = fmaf(aA.x, bj.y, Q[0]); Q[1] = fmaf(aA.y, bj.y, Q[1]);
        Q[2] = fmaf(aA.z, bj.y, Q[2]); Q[3] = fmaf(aA.w, bj.y, Q[3]);
        Q[4] = fmaf(aB.x, bj.y, Q[4]); Q[5] = fmaf(aB.y, bj.y, Q[5]);
        Q[6] = fmaf(aB.z, bj.y, Q[6]); Q[7] = fmaf(aB.w, bj.y, Q[7]);
        P[0] = fmaf(aC.x, bj.z, P[0]); P[1] = fmaf(aC.y, bj.z, P[1]);
        P[2] = fmaf(aC.z, bj.z, P[2]); P[3] = fmaf(aC.w, bj.z, P[3]);
        P[4] = fmaf(aD.x, bj.z, P[4]); P[5] = fmaf(aD.y, bj.z, P[5]);
        P[6] = fmaf(aD.z, bj.z, P[6]); P[7] = fmaf(aD.w, bj.z, P[7]);
        Q[0] = fmaf(aC.x, bj.w, Q[0]); Q[1] = fmaf(aC.y, bj.w, Q[1]);
        Q[2] = fmaf(aC.z, bj.w, Q[2]); Q[3] = fmaf(aC.w, bj.w, Q[3]);
        Q[4] = fmaf(aD.x, bj.w, Q[4]); Q[5] = fmaf(aD.y, bj.w, Q[5]);
        Q[6] = fmaf(aD.z, bj.w, Q[6]); Q[7] = fmaf(aD.w, bj.w, Q[7]);
    }

    const float bsqv = bsqA[t];
    const float cjv = cjA[t];
    float esv[8], s1v[8];
    #pragma unroll
    for (int mi = 0; mi < 8; ++mi) {
        float dist2 = asq[m0 + mi] + bsqv - 2.0f * P[mi];
        dist2 = fmaxf(dist2, 0.0f);
        const float x = sqrtf(dist2);
        const float e = KE * expf(-x);
        const float dotv = Q[mi] - cjv;
        const float w1v = e * dotv;
        const float w2v = e * (1.0f + x);
        w1Tm[(m0 + mi) * NTRAIN + t] = w1v;
        w2Tm[(m0 + mi) * NTRAIN + t] = w2v;
        esv[mi] = w2v * dotv;
        s1v[mi] = w1v;
    }
    #pragma unroll
    for (int off = 32; off > 0; off >>= 1) {
        #pragma unroll
        for (int mi = 0; mi < 8; ++mi) {
            esv[mi] += __shfl_down(esv[mi], off, 64);
            s1v[mi] += __shfl_down(s1v[mi], off, 64);
        }
    }
    if ((tid & 63) == 0) {
        #pragma unroll
        for (int mi = 0; mi < 8; ++mi) {
            atomicAdd(&EsAcc[m0 + mi], esv[mi]);
            atomicAdd(&S1[m0 + mi], s1v[mi]);
        }
    }
}

// pass 2: F1[m,d] += sum_t w1[m,t]*q*xs[t,d]; F2[m,d] += sum_t w2[m,t]*Jx[t,d].
// d = lane (coalesced xs/Jx loads in native [t][d] layout); w addresses depend only
// on blockIdx + loop index -> provably uniform -> SMEM s_load.
__global__ __launch_bounds__(256) void k_pass2(const float* __restrict__ xs_train,
                                               const float* __restrict__ Jx,
                                               const float* __restrict__ w1Tm,
                                               const float* __restrict__ w2Tm,
                                               float* __restrict__ F1acc,
                                               float* __restrict__ F2acc) {
    const int d = threadIdx.x;
    const int t0 = blockIdx.x * 128;
    const int m0 = blockIdx.y * 8;
    const bool act = d < DESC;
    const int dd = act ? d : 0;

    float G1[8] = {0.f, 0.f, 0.f, 0.f, 0.f, 0.f, 0.f, 0.f};
    float G2[8] = {0.f, 0.f, 0.f, 0.f, 0.f, 0.f, 0.f, 0.f};

    #pragma unroll 4
    for (int tt = 0; tt < 128; ++tt) {
        const int t = t0 + tt;
        const float bv = QS * xs_train[t * DESC + dd];
        const float jv = Jx[t * DESC + dd];
        #pragma unroll
        for (int mi = 0; mi < 8; ++mi) {
            const float w1 = w1Tm[(m0 + mi) * NTRAIN + t];
            const float w2 = w2Tm[(m0 + mi) * NTRAIN + t];
            G1[mi] = fmaf(w1, bv, G1[mi]);
            G2[mi] = fmaf(w2, jv, G2[mi]);
        }
    }
    if (act) {
        #pragma unroll
        for (int mi = 0; mi < 8; ++mi) {
            atomicAdd(&F1acc[(m0 + mi) * DESC + d], G1[mi]);
            atomicAdd(&F2acc[(m0 + mi) * DESC + d], G2[mi]);
        }
    }
}

// final assembly — coef, force scatter, Es
__global__ __launch_bounds__(256) void k_final(const float* __restrict__ Rs,
                                               const float* __restrict__ aT,
                                               const float* __restrict__ S1,
                                               const float* __restrict__ EsAcc,
                                               const float* __restrict__ F1acc,
                                               const float* __restrict__ F2acc,
                                               float* __restrict__ out) {
    const int m = blockIdx.x;
    __shared__ float R[NATOMS * 3];
    __shared__ float FsL[NATOMS * 3];
    const int tid = threadIdx.x;
    if (tid < NATOMS * 3) {
        R[tid] = Rs[m * NATOMS * 3 + tid];
        FsL[tid] = 0.0f;
    }
    __syncthreads();
    if (tid < DESC) {
        int i, j;
        pair_ij(tid, i, j);
        const float dx = R[i * 3 + 0] - R[j * 3 + 0];
        const float dy = R[i * 3 + 1] - R[j * 3 + 1];
        const float dz = R[i * 3 + 2] - R[j * 3 + 2];
        const float r2 = dx * dx + dy * dy + dz * dz;
        const float rinv = 1.0f / sqrtf(r2);
        const float a = aT[tid * NM + m];  // q/r
        const float F1 = a * S1[m] - F1acc[m * DESC + tid];
        const float Fx = (F1 - F2acc[m * DESC + tid]) * STDC;
        const float coef = Fx * (rinv * rinv * rinv);
        atomicAdd(&FsL[j * 3 + 0], coef * dx);
        atomicAdd(&FsL[j * 3 + 1], coef * dy);
        atomicAdd(&FsL[j * 3 + 2], coef * dz);
        atomicAdd(&FsL[i * 3 + 0], -coef * dx);
        atomicAdd(&FsL[i * 3 + 1], -coef * dy);
        atomicAdd(&FsL[i * 3 + 2], -coef * dz);
    }
    __syncthreads();
    if (tid < NATOMS * 3) out[NM + m * NATOMS * 3 + tid] = FsL[tid];
    if (tid == 0) out[m] = CC + (EsAcc[m] / QS) * STDC;
}

extern "C" void kernel_launch(void* const* d_in, const int* in_sizes, int n_in,
                              void* d_out, int out_size, void* d_ws, size_t ws_size,
                              hipStream_t stream) {
    const float* Rs = (const float*)d_in[0];
    const float* xs_train = (const float*)d_in[1];
    const float* Jx = (const float*)d_in[2];
    float* out = (float*)d_out;
    float* ws = (float*)d_ws;

    // zeroed prefix
    float* F1acc = ws;                         // 26880
    float* F2acc = ws + 26880;                 // 26880
    float* EsAcc = ws + 53760;                 // 128
    float* S1 = ws + 53888;                    // 128
    float* bsqA = ws + 54016;                  // 4096
    float* cjA = ws + 58112;                   // 4096  -> zero block ends at 62208
    // non-zeroed
    float* aT = ws + 62208;                    // 224*128 = 28672
    float* asq = ws + 90880;                   // 128
    float4* bjq = (float4*)(ws + 91008);       // 112*4096 float4 = 1835008 floats
    float* w1Tm = ws + 1926016;                // 524288
    float* w2Tm = ws + 2450304;                // 524288 -> end 2974592 floats (~11.9 MB)

    hipMemsetAsync(ws, 0, (size_t)62208 * sizeof(float), stream);

    k_prep<<<576, 256, 0, stream>>>(Rs, xs_train, Jx, bjq, aT, asq, bsqA, cjA);
    k_pass1<<<dim3(NTRAIN / 256, NM / 8), 256, 0, stream>>>(bjq, aT, asq, bsqA, cjA,
                                                            w1Tm, w2Tm, EsAcc, S1);
    k_pass2<<<dim3(NTRAIN / 128, NM / 8), 256, 0, stream>>>(xs_train, Jx, w1Tm, w2Tm,
                                                            F1acc, F2acc);
    k_final<<<NM, 256, 0, stream>>>(Rs, aT, S1, EsAcc, F1acc, F2acc, out);
}